// Round 2
// baseline (248.776 us; speedup 1.0000x reference)
//
#include <hip/hip_runtime.h>
#include <cstdint>

// Selection is on x directly: for t<0 the target is exactly -1 (t ∈ {-1,0,1}),
// so negative_loss = softplus(x), strictly increasing in x. Radix-select the
// k-th largest x among t<0 entries (exact, transcendental-free), then threshold
// by VALUE in loss-space: thr_nl = neg_loss(x_kth, -1), mask = (nl < thr_nl).
// Value-based compare reproduces the reference's tie semantics at the boundary.
//
// Radix split: 11 + 13 + 8 bits of the order-transformed x bit pattern.
// ws layout:
//   [0      ..  8192)  hist1 (2048 u32)
//   [8192   .. 40960)  hist2 (8192 u32)
//   [40960  .. 41984)  hist3 (256 u32)
//   [41984  .. 42000)  SelState
//   [49152  .. 49152+4N)  cached u-vals (transformed x; 0 sentinel for t>=0)

struct SelState {
    uint32_t prefix;   // selected high bits so far
    uint32_t k_rem;    // remaining rank within selected bin
    float    thr_nl;   // final loss-space threshold (valid when done)
    uint32_t done;
};

// order-preserving transform for signed floats: u monotone increasing in x
__device__ __forceinline__ uint32_t xform(uint32_t bits) {
    return ((int32_t)bits < 0) ? ~bits : (bits | 0x80000000u);
}
__device__ __forceinline__ float unxform(uint32_t u) {
    uint32_t bits = (u & 0x80000000u) ? (u ^ 0x80000000u) : ~u;
    return __uint_as_float(bits);
}

// precise (library) losses — the SAME expression is used for the threshold value
// (scan level 2) and the final mask compare, so rounding is self-consistent.
__device__ __forceinline__ float neg_loss(float x, float t) {
#pragma clang fp contract(off)
    return (fmaxf(-x, 0.0f) - x * t) + log1pf(expf(-fabsf(x)));
}
__device__ __forceinline__ float pos_loss(float x, float t) {
#pragma clang fp contract(off)
    return (fmaxf(x, 0.0f) - x * t) + log1pf(expf(-fabsf(x)));
}

#define NB1   2048   // 11-bit first pass
#define NCOPY 4      // replicated LDS histograms (cuts same-address atomic serialization)
#define HPAD  2049   // +1 pad so copies land in different banks

__global__ __launch_bounds__(256) void hist_pass1(
        const float* __restrict__ x, const float* __restrict__ t,
        uint32_t* __restrict__ uvals, uint32_t* __restrict__ hist, int n) {
    __shared__ uint32_t lh[NCOPY * HPAD];
    for (int i = threadIdx.x; i < NCOPY * HPAD; i += blockDim.x) lh[i] = 0;
    __syncthreads();
    uint32_t* my = &lh[(threadIdx.x & (NCOPY - 1)) * HPAD];

    const int n4 = n >> 2;
    const float4* x4 = (const float4*)x;
    const float4* t4 = (const float4*)t;
    const int stride = gridDim.x * blockDim.x;
    for (int i = blockIdx.x * blockDim.x + threadIdx.x; i < n4; i += stride) {
        float4 xv = x4[i];
        float4 tv = t4[i];
        uint32_t u0 = (tv.x < 0.0f) ? xform(__float_as_uint(xv.x)) : 0u;
        uint32_t u1 = (tv.y < 0.0f) ? xform(__float_as_uint(xv.y)) : 0u;
        uint32_t u2 = (tv.z < 0.0f) ? xform(__float_as_uint(xv.z)) : 0u;
        uint32_t u3 = (tv.w < 0.0f) ? xform(__float_as_uint(xv.w)) : 0u;
        if (uvals) ((uint4*)uvals)[i] = make_uint4(u0, u1, u2, u3);
        if (u0) atomicAdd(&my[u0 >> 21], 1u);
        if (u1) atomicAdd(&my[u1 >> 21], 1u);
        if (u2) atomicAdd(&my[u2 >> 21], 1u);
        if (u3) atomicAdd(&my[u3 >> 21], 1u);
    }
    if (blockIdx.x == 0) {  // tail
        for (int i = (n4 << 2) + threadIdx.x; i < n; i += blockDim.x) {
            uint32_t u = (t[i] < 0.0f) ? xform(__float_as_uint(x[i])) : 0u;
            if (uvals) uvals[i] = u;
            if (u) atomicAdd(&my[u >> 21], 1u);
        }
    }
    __syncthreads();
    for (int i = threadIdx.x; i < NB1; i += blockDim.x) {
        uint32_t c = lh[i] + lh[HPAD + i] + lh[2 * HPAD + i] + lh[3 * HPAD + i];
        if (c) atomicAdd(&hist[i], c);
    }
}

__global__ __launch_bounds__(256) void hist_refine(
        const float* __restrict__ x, const float* __restrict__ t,
        const uint32_t* __restrict__ uvals, int n,
        const SelState* __restrict__ st, uint32_t* __restrict__ hist,
        int match_shift, int bin_shift, uint32_t bin_mask) {
    extern __shared__ uint32_t lh[];
    SelState s = *st;
    if (s.done) return;  // uniform
    const uint32_t prefix = s.prefix;
    for (int i = threadIdx.x; i <= (int)bin_mask; i += blockDim.x) lh[i] = 0;
    __syncthreads();

    const int n4 = n >> 2;
    const int stride = gridDim.x * blockDim.x;
    const int tid0 = blockIdx.x * blockDim.x + threadIdx.x;
    if (uvals) {
        const uint4* u4 = (const uint4*)uvals;
        for (int i = tid0; i < n4; i += stride) {
            uint4 u = u4[i];
            if (u.x && (u.x >> match_shift) == prefix) atomicAdd(&lh[(u.x >> bin_shift) & bin_mask], 1u);
            if (u.y && (u.y >> match_shift) == prefix) atomicAdd(&lh[(u.y >> bin_shift) & bin_mask], 1u);
            if (u.z && (u.z >> match_shift) == prefix) atomicAdd(&lh[(u.z >> bin_shift) & bin_mask], 1u);
            if (u.w && (u.w >> match_shift) == prefix) atomicAdd(&lh[(u.w >> bin_shift) & bin_mask], 1u);
        }
        if (blockIdx.x == 0) {
            for (int i = (n4 << 2) + threadIdx.x; i < n; i += blockDim.x) {
                uint32_t u = uvals[i];
                if (u && (u >> match_shift) == prefix) atomicAdd(&lh[(u >> bin_shift) & bin_mask], 1u);
            }
        }
    } else {
        const float4* x4 = (const float4*)x;
        const float4* t4 = (const float4*)t;
        for (int i = tid0; i < n4; i += stride) {
            float4 xv = x4[i];
            float4 tv = t4[i];
            uint32_t u0 = (tv.x < 0.0f) ? xform(__float_as_uint(xv.x)) : 0u;
            uint32_t u1 = (tv.y < 0.0f) ? xform(__float_as_uint(xv.y)) : 0u;
            uint32_t u2 = (tv.z < 0.0f) ? xform(__float_as_uint(xv.z)) : 0u;
            uint32_t u3 = (tv.w < 0.0f) ? xform(__float_as_uint(xv.w)) : 0u;
            if (u0 && (u0 >> match_shift) == prefix) atomicAdd(&lh[(u0 >> bin_shift) & bin_mask], 1u);
            if (u1 && (u1 >> match_shift) == prefix) atomicAdd(&lh[(u1 >> bin_shift) & bin_mask], 1u);
            if (u2 && (u2 >> match_shift) == prefix) atomicAdd(&lh[(u2 >> bin_shift) & bin_mask], 1u);
            if (u3 && (u3 >> match_shift) == prefix) atomicAdd(&lh[(u3 >> bin_shift) & bin_mask], 1u);
        }
        if (blockIdx.x == 0) {
            for (int i = (n4 << 2) + threadIdx.x; i < n; i += blockDim.x) {
                uint32_t u = (t[i] < 0.0f) ? xform(__float_as_uint(x[i])) : 0u;
                if (u && (u >> match_shift) == prefix) atomicAdd(&lh[(u >> bin_shift) & bin_mask], 1u);
            }
        }
    }
    __syncthreads();
    for (int i = threadIdx.x; i <= (int)bin_mask; i += blockDim.x) {
        uint32_t c = lh[i];
        if (c) atomicAdd(&hist[i], c);
    }
}

// Single block, 256 threads. Finds the bin holding the k-th LARGEST element.
// level 0: k from kptr (early-finish: k==0 -> thr=+inf keep-all; k>total -> thr=0 drop-all)
// level 1: appends 13 bits; level 2: appends 8 bits, converts to loss-space threshold.
__global__ __launch_bounds__(256) void scan_select(
        const uint32_t* __restrict__ hist, int nbins,
        SelState* __restrict__ st, const int* __restrict__ kptr, int level) {
    __shared__ uint32_t part[256];
    __shared__ SelState sst;
    __shared__ uint32_t sk;
    const int tid = threadIdx.x;
    if (tid == 0) {
        sst = *st;
        if (level == 0) {
            int kk = *kptr;
            sk = (kk > 0) ? (uint32_t)kk : 0u;
        } else {
            sk = sst.k_rem;
        }
    }
    __syncthreads();
    if (level > 0 && sst.done) return;
    const uint32_t k = sk;

    const int ch = nbins >> 8;  // bins per thread: 8 / 32 / 1
    uint32_t cnt[32];
    uint32_t lsum = 0;
    for (int j = 0; j < ch; ++j) {
        cnt[j] = hist[tid * ch + j];
        lsum += cnt[j];
    }
    part[tid] = lsum;
    __syncthreads();
    // inclusive suffix sum: part[t] = sum_{j>=t}
    for (int off = 1; off < 256; off <<= 1) {
        uint32_t add = (tid + off < 256) ? part[tid + off] : 0u;
        __syncthreads();
        part[tid] += add;
        __syncthreads();
    }
    const uint32_t total = part[0];

    if (level == 0) {
        if (k == 0) {
            if (tid == 0) { st->done = 1; st->thr_nl = __int_as_float(0x7F800000); }
            return;
        }
        if (k > total) {
            if (tid == 0) { st->done = 1; st->thr_nl = 0.0f; }
            return;
        }
    }

    uint32_t A = (tid < 255) ? part[tid + 1] : 0u;  // count in bins strictly above my chunk
    for (int j = ch - 1; j >= 0; --j) {
        uint32_t c = cnt[j];
        if (A < k && k <= A + c) {  // exactly one thread/bin hits this
            uint32_t bin = (uint32_t)(tid * ch + j);
            uint32_t krem = k - A;
            if (level == 0) {
                st->prefix = bin;           // 11 bits
                st->k_rem = krem;
            } else if (level == 1) {
                st->prefix = (sst.prefix << 13) | bin;   // 24 bits
                st->k_rem = krem;
            } else {
                uint32_t u = (sst.prefix << 8) | bin;    // full 32 bits
                float xk = unxform(u);
                st->thr_nl = neg_loss(xk, -1.0f);  // same expression as final mask
                st->done = 1;
            }
        }
        A += c;
    }
}

__global__ __launch_bounds__(256) void final_pass(
        const float* __restrict__ x, const float* __restrict__ t,
        const SelState* __restrict__ st, float* __restrict__ out, int n) {
    const float thr = st->thr_nl;
    const int n4 = n >> 2;
    const float4* x4 = (const float4*)x;
    const float4* t4 = (const float4*)t;
    float4* o4 = (float4*)out;
    const int stride = gridDim.x * blockDim.x;
    for (int i = blockIdx.x * blockDim.x + threadIdx.x; i < n4; i += stride) {
        float4 xv = x4[i];
        float4 tv = t4[i];
        float4 r;
        {
            float xx = xv.x, tt = tv.x;
            r.x = (tt > 0.0f) ? pos_loss(xx, tt)
                : (tt < 0.0f) ? ((neg_loss(xx, tt) < thr) ? neg_loss(xx, tt) : 0.0f) : 0.0f;
        }
        {
            float xx = xv.y, tt = tv.y;
            r.y = (tt > 0.0f) ? pos_loss(xx, tt)
                : (tt < 0.0f) ? ((neg_loss(xx, tt) < thr) ? neg_loss(xx, tt) : 0.0f) : 0.0f;
        }
        {
            float xx = xv.z, tt = tv.z;
            r.z = (tt > 0.0f) ? pos_loss(xx, tt)
                : (tt < 0.0f) ? ((neg_loss(xx, tt) < thr) ? neg_loss(xx, tt) : 0.0f) : 0.0f;
        }
        {
            float xx = xv.w, tt = tv.w;
            r.w = (tt > 0.0f) ? pos_loss(xx, tt)
                : (tt < 0.0f) ? ((neg_loss(xx, tt) < thr) ? neg_loss(xx, tt) : 0.0f) : 0.0f;
        }
        o4[i] = r;
    }
    if (blockIdx.x == 0) {
        for (int i = (n4 << 2) + threadIdx.x; i < n; i += blockDim.x) {
            float xx = x[i], tt = t[i];
            out[i] = (tt > 0.0f) ? pos_loss(xx, tt)
                   : (tt < 0.0f) ? ((neg_loss(xx, tt) < thr) ? neg_loss(xx, tt) : 0.0f) : 0.0f;
        }
    }
}

extern "C" void kernel_launch(void* const* d_in, const int* in_sizes, int n_in,
                              void* d_out, int out_size, void* d_ws, size_t ws_size,
                              hipStream_t stream) {
    const float* x = (const float*)d_in[0];
    const float* t = (const float*)d_in[1];
    const int* kptr = (const int*)d_in[2];
    float* out = (float*)d_out;
    const int n = in_sizes[0];
    if (n <= 0) return;

    char* ws = (char*)d_ws;
    uint32_t* hist1 = (uint32_t*)(ws + 0);       // 2048
    uint32_t* hist2 = (uint32_t*)(ws + 8192);    // 8192
    uint32_t* hist3 = (uint32_t*)(ws + 40960);   // 256
    SelState* st = (SelState*)(ws + 41984);
    const bool cached = ws_size >= (size_t)49152 + (size_t)n * 4u;
    uint32_t* uvals = cached ? (uint32_t*)(ws + 49152) : nullptr;

    hipMemsetAsync(d_ws, 0, 42112, stream);  // hists + state

    const int n4 = n >> 2;
    int blocks = (n4 + 255) / 256;
    if (blocks > 2048) blocks = 2048;
    if (blocks < 1) blocks = 1;

    hist_pass1<<<blocks, 256, 0, stream>>>(x, t, uvals, hist1, n);
    scan_select<<<1, 256, 0, stream>>>(hist1, 2048, st, kptr, 0);
    hist_refine<<<blocks, 256, 8192 * 4, stream>>>(x, t, uvals, n, st, hist2, 21, 8, 0x1FFFu);
    scan_select<<<1, 256, 0, stream>>>(hist2, 8192, st, kptr, 1);
    hist_refine<<<blocks, 256, 256 * 4, stream>>>(x, t, uvals, n, st, hist3, 8, 0, 0xFFu);
    scan_select<<<1, 256, 0, stream>>>(hist3, 256, st, kptr, 2);
    final_pass<<<blocks, 256, 0, stream>>>(x, t, st, out, n);
}